// Round 1
// baseline (828.597 us; speedup 1.0000x reference)
//
#include <hip/hip_runtime.h>

// Problem constants (from reference)
#define FDIM 512
#define TDK  0.1f   // TIME_DECAY
#define DTs  0.2f   // DIFF_T / NUM_STEPS
#define EPSv 1e-5f

using bf16x8  = __attribute__((ext_vector_type(8))) __bf16;
using floatx4 = __attribute__((ext_vector_type(4))) float;
using ushort8 = __attribute__((ext_vector_type(8))) unsigned short;

__device__ __forceinline__ unsigned short f2bf(float f) {
  unsigned int u = __float_as_uint(f);
  u += 0x7fffu + ((u >> 16) & 1u);   // RNE
  return (unsigned short)(u >> 16);
}

// ---------------- ts.max() over timestamps (graph_time folded in later) -------
__global__ __launch_bounds__(256) void tsmax_kernel(const float* __restrict__ ts, int E,
                                                    float* __restrict__ out) {
  float m = 0.f;  // timestamps >= 0
  for (int i = blockIdx.x * blockDim.x + threadIdx.x; i < E; i += gridDim.x * blockDim.x)
    m = fmaxf(m, ts[i]);
  for (int off = 32; off; off >>= 1) m = fmaxf(m, __shfl_down(m, off));
  __shared__ float sm[4];
  int wid = threadIdx.x >> 6, lane = threadIdx.x & 63;
  if (lane == 0) sm[wid] = m;
  __syncthreads();
  if (threadIdx.x == 0) {
    float mm = fmaxf(fmaxf(sm[0], sm[1]), fmaxf(sm[2], sm[3]));
    atomicMax((int*)out, __float_as_int(mm));  // all values positive -> int order == float order
  }
}

// -------- per-edge decay weight + weighted degree (dst) + CSR row counts ------
__global__ __launch_bounds__(256) void edge_w_deg(const int* __restrict__ src, const int* __restrict__ dst,
                                                  const float* __restrict__ ts, const float* __restrict__ tsmax_p,
                                                  const int* __restrict__ gt_p,
                                                  float* __restrict__ w, float* __restrict__ deg,
                                                  int* __restrict__ cnt, int E, int N) {
  int e = blockIdx.x * blockDim.x + threadIdx.x;
  int total = E + N;
  if (e >= total) return;
  float gtf = (float)(*gt_p);
  float tm = fmaxf(*tsmax_p, gtf);
  int d; float t;
  if (e < E) { d = dst[e]; t = ts[e]; }
  else       { d = e - E;  t = gtf; }
  float wv = expf(-TDK * (tm - t));
  w[e] = wv;
  atomicAdd(&deg[d], wv);
  atomicAdd(&cnt[d], 1);
}

__global__ __launch_bounds__(256) void dinv_kernel(const float* __restrict__ deg, float* __restrict__ dinv, int N) {
  int i = blockIdx.x * blockDim.x + threadIdx.x;
  if (i >= N) return;
  float d = deg[i];
  dinv[i] = (d > 0.f) ? rsqrtf(d) : 0.f;
}

// ---------------- single-block exclusive scan for CSR offsets -----------------
__global__ __launch_bounds__(256) void scan_offsets(const int* __restrict__ cnt, int* __restrict__ offs,
                                                    int* __restrict__ cursor, int n) {
  __shared__ int sums[256];
  int tid = threadIdx.x;
  int chunk = (n + 255) >> 8;
  int start = tid * chunk;
  int end = min(start + chunk, n);
  int s = 0;
  for (int i = start; i < end; ++i) s += cnt[i];
  sums[tid] = s;
  __syncthreads();
  for (int off = 1; off < 256; off <<= 1) {
    int v = (tid >= off) ? sums[tid - off] : 0;
    __syncthreads();
    sums[tid] += v;
    __syncthreads();
  }
  int prefix = (tid == 0) ? 0 : sums[tid - 1];
  for (int i = start; i < end; ++i) {
    offs[i] = prefix; cursor[i] = prefix; prefix += cnt[i];
  }
  if (tid == 255) offs[n] = prefix;
}

// -------- scatter edges into CSR (col=src, val = dinv[src]*w*dinv[dst]) -------
__global__ __launch_bounds__(256) void scatter_kernel(const int* __restrict__ src, const int* __restrict__ dst,
                                                      const float* __restrict__ w, const float* __restrict__ dinv,
                                                      int* __restrict__ cursor, int* __restrict__ col,
                                                      float* __restrict__ val, int E, int N) {
  int e = blockIdx.x * blockDim.x + threadIdx.x;
  if (e >= E + N) return;
  int s, d;
  if (e < E) { s = src[e]; d = dst[e]; }
  else       { s = d = e - E; }
  int pos = atomicAdd(&cursor[d], 1);
  col[pos] = s;
  val[pos] = dinv[s] * w[e] * dinv[d];
}

// ------------- one diffusion step: h_out = (1-dt)h_in + dt*(A h_in) -----------
// one block per dst row; 256 threads cover 512 features as float2
__global__ __launch_bounds__(256) void spmm_step(const int* __restrict__ offs, const int* __restrict__ col,
                                                 const float* __restrict__ val,
                                                 const float* __restrict__ h_in, float* __restrict__ h_out) {
  int d = blockIdx.x;
  int t = threadIdx.x;
  int f = t * 2;
  int s = offs[d], e = offs[d + 1];
  float ax = 0.f, ay = 0.f;
  for (int j = s; j < e; ++j) {
    int c = col[j];
    float v = val[j];
    float2 hv = *(const float2*)(h_in + (size_t)c * FDIM + f);
    ax += v * hv.x; ay += v * hv.y;
  }
  float2 hd = *(const float2*)(h_in + (size_t)d * FDIM + f);
  float2 o;
  o.x = hd.x + DTs * (ax - hd.x);
  o.y = hd.y + DTs * (ay - hd.y);
  *(float2*)(h_out + (size_t)d * FDIM + f) = o;
}

// ------------------------------ fp32 -> bf16 cast -----------------------------
__global__ __launch_bounds__(256) void cast_bf16(const float* __restrict__ srcp,
                                                 unsigned short* __restrict__ dstp, int n8) {
  int i = blockIdx.x * blockDim.x + threadIdx.x;
  if (i >= n8) return;
  const float4 v0 = *(const float4*)(srcp + (size_t)i * 8);
  const float4 v1 = *(const float4*)(srcp + (size_t)i * 8 + 4);
  ushort8 o;
  o[0] = f2bf(v0.x); o[1] = f2bf(v0.y); o[2] = f2bf(v0.z); o[3] = f2bf(v0.w);
  o[4] = f2bf(v1.x); o[5] = f2bf(v1.y); o[6] = f2bf(v1.z); o[7] = f2bf(v1.w);
  *(ushort8*)(dstp + (size_t)i * 8) = o;
}

// --------------------- bf16 MFMA GEMM: C = A @ B^T (B is [n][k]) --------------
// block = 256 thr (4 waves in 2x2), tile 128x128, BK=32, LDS row stride 40 (pad)
// If C1 != nullptr: C = relu(C1 + bias) + A@B^T  (fused epilogue for GEMM2)
__global__ __launch_bounds__(256) void gemm_bt(const __bf16* __restrict__ A, const __bf16* __restrict__ B,
                                               float* __restrict__ C, const float* __restrict__ C1,
                                               const float* __restrict__ bias, int M) {
  __shared__ __bf16 a_s[128 * 40];
  __shared__ __bf16 b_s[128 * 40];
  int tid = threadIdx.x;
  int wid = tid >> 6, lane = tid & 63;
  int wm = wid & 1, wn = wid >> 1;
  int lane15 = lane & 15, quad = lane >> 4;
  int m0 = blockIdx.x * 128;
  int n0 = blockIdx.y * 128;

  floatx4 acc[4][4];
  floatx4 z4; z4[0] = 0.f; z4[1] = 0.f; z4[2] = 0.f; z4[3] = 0.f;
#pragma unroll
  for (int im = 0; im < 4; ++im)
#pragma unroll
    for (int in = 0; in < 4; ++in) acc[im][in] = z4;

  for (int kt = 0; kt < FDIM; kt += 32) {
    // stage A (128x32) — row-clamped (out-of-range rows never stored in epilogue)
#pragma unroll
    for (int i = tid; i < 512; i += 256) {
      int row = i >> 2, seg = i & 3;
      int gm = m0 + row; if (gm >= M) gm = M - 1;
      bf16x8 v = *(const bf16x8*)(A + (size_t)gm * FDIM + kt + seg * 8);
      *(bf16x8*)(a_s + row * 40 + seg * 8) = v;
    }
    // stage B (128x32); N=512 divides evenly
#pragma unroll
    for (int i = tid; i < 512; i += 256) {
      int row = i >> 2, seg = i & 3;
      bf16x8 v = *(const bf16x8*)(B + (size_t)(n0 + row) * FDIM + kt + seg * 8);
      *(bf16x8*)(b_s + row * 40 + seg * 8) = v;
    }
    __syncthreads();
    bf16x8 af[4], bf[4];
#pragma unroll
    for (int im = 0; im < 4; ++im)
      af[im] = *(const bf16x8*)(a_s + (wm * 64 + im * 16 + lane15) * 40 + quad * 8);
#pragma unroll
    for (int in = 0; in < 4; ++in)
      bf[in] = *(const bf16x8*)(b_s + (wn * 64 + in * 16 + lane15) * 40 + quad * 8);
#pragma unroll
    for (int im = 0; im < 4; ++im)
#pragma unroll
      for (int in = 0; in < 4; ++in)
        acc[im][in] = __builtin_amdgcn_mfma_f32_16x16x32_bf16(af[im], bf[in], acc[im][in], 0, 0, 0);
    __syncthreads();
  }

  // epilogue: C/D layout col=lane&15, row=quad*4+reg
#pragma unroll
  for (int im = 0; im < 4; ++im) {
#pragma unroll
    for (int in = 0; in < 4; ++in) {
#pragma unroll
      for (int r = 0; r < 4; ++r) {
        int m = m0 + wm * 64 + im * 16 + quad * 4 + r;
        int n = n0 + wn * 64 + in * 16 + lane15;
        if (m < M) {
          float v = acc[im][in][r];
          if (C1) {
            float p = C1[(size_t)m * FDIM + n] + bias[n];
            v += fmaxf(p, 0.f);
          }
          C[(size_t)m * FDIM + n] = v;
        }
      }
    }
  }
}

// ------------------------------ rowwise LayerNorm -----------------------------
__global__ __launch_bounds__(256) void ln_kernel(const float* __restrict__ pre, const float* __restrict__ gamma,
                                                 const float* __restrict__ beta, float* __restrict__ out) {
  int row = blockIdx.x, t = threadIdx.x;
  float2 v = *(const float2*)(pre + (size_t)row * FDIM + t * 2);
  float s = v.x + v.y;
  float ss = v.x * v.x + v.y * v.y;
  for (int off = 32; off; off >>= 1) { s += __shfl_down(s, off); ss += __shfl_down(ss, off); }
  __shared__ float sm[4], sm2[4];
  int wid = t >> 6, lane = t & 63;
  if (lane == 0) { sm[wid] = s; sm2[wid] = ss; }
  __syncthreads();
  if (t == 0) {
    float a = sm[0] + sm[1] + sm[2] + sm[3];
    float b = sm2[0] + sm2[1] + sm2[2] + sm2[3];
    sm[0] = a; sm2[0] = b;
  }
  __syncthreads();
  float mu = sm[0] * (1.f / FDIM);
  float var = sm2[0] * (1.f / FDIM) - mu * mu;
  float inv = rsqrtf(var + EPSv);
  float2 g  = *(const float2*)(gamma + t * 2);
  float2 bb = *(const float2*)(beta + t * 2);
  float2 o;
  o.x = (v.x - mu) * inv * g.x + bb.x;
  o.y = (v.y - mu) * inv * g.y + bb.y;
  *(float2*)(out + (size_t)row * FDIM + t * 2) = o;
}

extern "C" void kernel_launch(void* const* d_in, const int* in_sizes, int n_in,
                              void* d_out, int out_size, void* d_ws, size_t ws_size,
                              hipStream_t stream) {
  const float* x     = (const float*)d_in[0];
  const int*   ei    = (const int*)d_in[1];
  const float* ts    = (const float*)d_in[2];
  const float* W_t   = (const float*)d_in[3];
  const float* b_t   = (const float*)d_in[4];
  const float* W_r   = (const float*)d_in[5];
  const float* gamma = (const float*)d_in[6];
  const float* beta  = (const float*)d_in[7];
  const int*   gt    = (const int*)d_in[8];

  const int E = in_sizes[2];
  const int N = in_sizes[0] / FDIM;
  const int* src = ei;
  const int* dst = ei + E;
  const int totE = E + N;

  // ---- workspace carve (all regions fully rewritten every call) ----
  char* base = (char*)d_ws;
  size_t off = 0;
  auto carve = [&](size_t bytes) -> char* {
    char* r = base + off;
    off = (off + bytes + 255) & ~(size_t)255;
    return r;
  };
  float* tsmax = (float*)carve(4);
  float* deg   = (float*)carve((size_t)N * 4);
  int*   cnt   = (int*)  carve((size_t)N * 4);
  size_t zero_bytes = off;                       // tsmax+deg+cnt need zeroing
  float* dinv  = (float*)carve((size_t)N * 4);
  int*   offs  = (int*)  carve((size_t)(N + 1) * 4);
  int*   cursor= (int*)  carve((size_t)N * 4);
  float* w     = (float*)carve((size_t)totE * 4);
  int*   col   = (int*)  carve((size_t)totE * 4);
  float* val   = (float*)carve((size_t)totE * 4);
  float* h_a   = (float*)carve((size_t)N * FDIM * 4);
  float* h_b   = (float*)carve((size_t)N * FDIM * 4);
  unsigned short* hb  = (unsigned short*)carve((size_t)N * FDIM * 2);
  unsigned short* xb  = (unsigned short*)carve((size_t)N * FDIM * 2);
  unsigned short* wtb = (unsigned short*)carve((size_t)FDIM * FDIM * 2);
  unsigned short* wrb = (unsigned short*)carve((size_t)FDIM * FDIM * 2);
  float* C1    = h_b;   // alias: free after diffusion
  float* preLN = h_a;   // alias: free after cast to hb

  hipMemsetAsync(d_ws, 0, zero_bytes, stream);

  tsmax_kernel<<<64, 256, 0, stream>>>(ts, E, tsmax);
  edge_w_deg<<<(totE + 255) / 256, 256, 0, stream>>>(src, dst, ts, tsmax, gt, w, deg, cnt, E, N);
  dinv_kernel<<<(N + 255) / 256, 256, 0, stream>>>(deg, dinv, N);
  scan_offsets<<<1, 256, 0, stream>>>(cnt, offs, cursor, N);
  scatter_kernel<<<(totE + 255) / 256, 256, 0, stream>>>(src, dst, w, dinv, cursor, col, val, E, N);

  // 5 Euler steps: x -> h_a -> h_b -> h_a -> h_b -> h_a
  spmm_step<<<N, 256, 0, stream>>>(offs, col, val, x,   h_a);
  spmm_step<<<N, 256, 0, stream>>>(offs, col, val, h_a, h_b);
  spmm_step<<<N, 256, 0, stream>>>(offs, col, val, h_b, h_a);
  spmm_step<<<N, 256, 0, stream>>>(offs, col, val, h_a, h_b);
  spmm_step<<<N, 256, 0, stream>>>(offs, col, val, h_b, h_a);

  // casts to bf16
  int n8x = N * FDIM / 8;
  cast_bf16<<<(n8x + 255) / 256, 256, 0, stream>>>(h_a, hb, n8x);
  cast_bf16<<<(n8x + 255) / 256, 256, 0, stream>>>(x,   xb, n8x);
  int n8w = FDIM * FDIM / 8;
  cast_bf16<<<(n8w + 255) / 256, 256, 0, stream>>>(W_t, wtb, n8w);
  cast_bf16<<<(n8w + 255) / 256, 256, 0, stream>>>(W_r, wrb, n8w);

  // GEMM1: C1 = h @ W_t^T ; GEMM2: preLN = relu(C1 + b_t) + x @ W_r^T
  dim3 gg((N + 127) / 128, FDIM / 128);
  gemm_bt<<<gg, 256, 0, stream>>>((const __bf16*)hb, (const __bf16*)wtb, C1, nullptr, nullptr, N);
  gemm_bt<<<gg, 256, 0, stream>>>((const __bf16*)xb, (const __bf16*)wrb, preLN, C1, b_t, N);

  ln_kernel<<<N, 256, 0, stream>>>(preLN, gamma, beta, (float*)d_out);
}

// Round 2
// 701.985 us; speedup vs baseline: 1.1804x; 1.1804x over previous
//
#include <hip/hip_runtime.h>

// Problem constants (from reference)
#define FDIM 512
#define TDK  0.1f   // TIME_DECAY
#define DTs  0.2f   // DIFF_T / NUM_STEPS
#define EPSv 1e-5f

using bf16x8  = __attribute__((ext_vector_type(8))) __bf16;
using floatx4 = __attribute__((ext_vector_type(4))) float;
using ushort8 = __attribute__((ext_vector_type(8))) unsigned short;

__device__ __forceinline__ unsigned short f2bf(float f) {
  unsigned int u = __float_as_uint(f);
  u += 0x7fffu + ((u >> 16) & 1u);   // RNE
  return (unsigned short)(u >> 16);
}

// ---------------- ts.max() over timestamps (graph_time folded in later) -------
__global__ __launch_bounds__(256) void tsmax_kernel(const float* __restrict__ ts, int E,
                                                    float* __restrict__ out) {
  float m = 0.f;  // timestamps >= 0
  for (int i = blockIdx.x * blockDim.x + threadIdx.x; i < E; i += gridDim.x * blockDim.x)
    m = fmaxf(m, ts[i]);
  for (int off = 32; off; off >>= 1) m = fmaxf(m, __shfl_down(m, off));
  __shared__ float sm[4];
  int wid = threadIdx.x >> 6, lane = threadIdx.x & 63;
  if (lane == 0) sm[wid] = m;
  __syncthreads();
  if (threadIdx.x == 0) {
    float mm = fmaxf(fmaxf(sm[0], sm[1]), fmaxf(sm[2], sm[3]));
    atomicMax((int*)out, __float_as_int(mm));  // positive floats: int order == float order
  }
}

// -------- per-edge decay weight + weighted degree (dst) + CSR row counts ------
__global__ __launch_bounds__(256) void edge_w_deg(const int* __restrict__ src, const int* __restrict__ dst,
                                                  const float* __restrict__ ts, const float* __restrict__ tsmax_p,
                                                  const int* __restrict__ gt_p,
                                                  float* __restrict__ w, float* __restrict__ deg,
                                                  int* __restrict__ cnt, int E, int N) {
  int e = blockIdx.x * blockDim.x + threadIdx.x;
  int total = E + N;
  if (e >= total) return;
  float gtf = (float)(*gt_p);
  float tm = fmaxf(*tsmax_p, gtf);
  int d; float t;
  if (e < E) { d = dst[e]; t = ts[e]; }
  else       { d = e - E;  t = gtf; }
  float wv = expf(-TDK * (tm - t));
  w[e] = wv;
  atomicAdd(&deg[d], wv);
  atomicAdd(&cnt[d], 1);
}

__global__ __launch_bounds__(256) void dinv_kernel(const float* __restrict__ deg, float* __restrict__ dinv, int N) {
  int i = blockIdx.x * blockDim.x + threadIdx.x;
  if (i >= N) return;
  float d = deg[i];
  dinv[i] = (d > 0.f) ? rsqrtf(d) : 0.f;
}

// ---------------- single-block exclusive scan for CSR offsets -----------------
__global__ __launch_bounds__(256) void scan_offsets(const int* __restrict__ cnt, int* __restrict__ offs,
                                                    int* __restrict__ cursor, int n) {
  __shared__ int sums[256];
  int tid = threadIdx.x;
  int chunk = (n + 255) >> 8;
  int start = tid * chunk;
  int end = min(start + chunk, n);
  int s = 0;
  for (int i = start; i < end; ++i) s += cnt[i];
  sums[tid] = s;
  __syncthreads();
  for (int off = 1; off < 256; off <<= 1) {
    int v = (tid >= off) ? sums[tid - off] : 0;
    __syncthreads();
    sums[tid] += v;
    __syncthreads();
  }
  int prefix = (tid == 0) ? 0 : sums[tid - 1];
  for (int i = start; i < end; ++i) {
    offs[i] = prefix; cursor[i] = prefix; prefix += cnt[i];
  }
  if (tid == 255) offs[n] = prefix;
}

// -------- scatter edges into CSR (col=src, val = dinv[src]*w*dinv[dst]) -------
__global__ __launch_bounds__(256) void scatter_kernel(const int* __restrict__ src, const int* __restrict__ dst,
                                                      const float* __restrict__ w, const float* __restrict__ dinv,
                                                      int* __restrict__ cursor, int* __restrict__ col,
                                                      float* __restrict__ val, int E, int N) {
  int e = blockIdx.x * blockDim.x + threadIdx.x;
  if (e >= E + N) return;
  int s, d;
  if (e < E) { s = src[e]; d = dst[e]; }
  else       { s = d = e - E; }
  int pos = atomicAdd(&cursor[d], 1);
  col[pos] = s;
  val[pos] = dinv[s] * w[e] * dinv[d];
}

// ------------- one diffusion step, bf16 state: h_out = (1-dt)h_in + dt*(A h_in)
// one block per dst row; 256 threads cover 512 features as bf16x2 (4 B/lane)
// fp32 accumulate; bf16 storage halves the random-gather HBM traffic
__global__ __launch_bounds__(256) void spmm_step_bf16(const int* __restrict__ offs, const int* __restrict__ col,
                                                      const float* __restrict__ val,
                                                      const unsigned short* __restrict__ h_in,
                                                      unsigned short* __restrict__ h_out) {
  int d = blockIdx.x;
  int t = threadIdx.x;
  int f = t * 2;
  int s = offs[d], e = offs[d + 1];
  float ax = 0.f, ay = 0.f;
  for (int j = s; j < e; ++j) {
    int c = col[j];
    float v = val[j];
    unsigned int u = *(const unsigned int*)(h_in + (size_t)c * FDIM + f);
    float hx = __uint_as_float((u & 0x0000ffffu) << 16);
    float hy = __uint_as_float(u & 0xffff0000u);
    ax += v * hx; ay += v * hy;
  }
  unsigned int ud = *(const unsigned int*)(h_in + (size_t)d * FDIM + f);
  float hdx = __uint_as_float((ud & 0x0000ffffu) << 16);
  float hdy = __uint_as_float(ud & 0xffff0000u);
  float ox = hdx + DTs * (ax - hdx);
  float oy = hdy + DTs * (ay - hdy);
  unsigned int o = (unsigned int)f2bf(ox) | ((unsigned int)f2bf(oy) << 16);
  *(unsigned int*)(h_out + (size_t)d * FDIM + f) = o;
}

// ------------------------------ fp32 -> bf16 cast -----------------------------
__global__ __launch_bounds__(256) void cast_bf16(const float* __restrict__ srcp,
                                                 unsigned short* __restrict__ dstp, int n8) {
  int i = blockIdx.x * blockDim.x + threadIdx.x;
  if (i >= n8) return;
  const float4 v0 = *(const float4*)(srcp + (size_t)i * 8);
  const float4 v1 = *(const float4*)(srcp + (size_t)i * 8 + 4);
  ushort8 o;
  o[0] = f2bf(v0.x); o[1] = f2bf(v0.y); o[2] = f2bf(v0.z); o[3] = f2bf(v0.w);
  o[4] = f2bf(v1.x); o[5] = f2bf(v1.y); o[6] = f2bf(v1.z); o[7] = f2bf(v1.w);
  *(ushort8*)(dstp + (size_t)i * 8) = o;
}

// --------------------- bf16 MFMA GEMM: C = A @ B^T (B is [n][k]) --------------
// block = 256 thr (4 waves in 2x2), tile 128x128, BK=32, LDS row stride 40 (pad)
// If C1 != nullptr: C = relu(C1 + bias) + A@B^T  (fused epilogue for GEMM2)
__global__ __launch_bounds__(256) void gemm_bt(const __bf16* __restrict__ A, const __bf16* __restrict__ B,
                                               float* __restrict__ C, const float* __restrict__ C1,
                                               const float* __restrict__ bias, int M) {
  __shared__ __bf16 a_s[128 * 40];
  __shared__ __bf16 b_s[128 * 40];
  int tid = threadIdx.x;
  int wid = tid >> 6, lane = tid & 63;
  int wm = wid & 1, wn = wid >> 1;
  int lane15 = lane & 15, quad = lane >> 4;
  int m0 = blockIdx.x * 128;
  int n0 = blockIdx.y * 128;

  floatx4 acc[4][4];
  floatx4 z4; z4[0] = 0.f; z4[1] = 0.f; z4[2] = 0.f; z4[3] = 0.f;
#pragma unroll
  for (int im = 0; im < 4; ++im)
#pragma unroll
    for (int in = 0; in < 4; ++in) acc[im][in] = z4;

  for (int kt = 0; kt < FDIM; kt += 32) {
#pragma unroll
    for (int i = tid; i < 512; i += 256) {
      int row = i >> 2, seg = i & 3;
      int gm = m0 + row; if (gm >= M) gm = M - 1;
      bf16x8 v = *(const bf16x8*)(A + (size_t)gm * FDIM + kt + seg * 8);
      *(bf16x8*)(a_s + row * 40 + seg * 8) = v;
    }
#pragma unroll
    for (int i = tid; i < 512; i += 256) {
      int row = i >> 2, seg = i & 3;
      bf16x8 v = *(const bf16x8*)(B + (size_t)(n0 + row) * FDIM + kt + seg * 8);
      *(bf16x8*)(b_s + row * 40 + seg * 8) = v;
    }
    __syncthreads();
    bf16x8 af[4], bf[4];
#pragma unroll
    for (int im = 0; im < 4; ++im)
      af[im] = *(const bf16x8*)(a_s + (wm * 64 + im * 16 + lane15) * 40 + quad * 8);
#pragma unroll
    for (int in = 0; in < 4; ++in)
      bf[in] = *(const bf16x8*)(b_s + (wn * 64 + in * 16 + lane15) * 40 + quad * 8);
#pragma unroll
    for (int im = 0; im < 4; ++im)
#pragma unroll
      for (int in = 0; in < 4; ++in)
        acc[im][in] = __builtin_amdgcn_mfma_f32_16x16x32_bf16(af[im], bf[in], acc[im][in], 0, 0, 0);
    __syncthreads();
  }

  // epilogue: C/D layout col=lane&15, row=quad*4+reg
#pragma unroll
  for (int im = 0; im < 4; ++im) {
#pragma unroll
    for (int in = 0; in < 4; ++in) {
#pragma unroll
      for (int r = 0; r < 4; ++r) {
        int m = m0 + wm * 64 + im * 16 + quad * 4 + r;
        int n = n0 + wn * 64 + in * 16 + lane15;
        if (m < M) {
          float v = acc[im][in][r];
          if (C1) {
            float p = C1[(size_t)m * FDIM + n] + bias[n];
            v += fmaxf(p, 0.f);
          }
          C[(size_t)m * FDIM + n] = v;
        }
      }
    }
  }
}

// ------------------------------ rowwise LayerNorm -----------------------------
__global__ __launch_bounds__(256) void ln_kernel(const float* __restrict__ pre, const float* __restrict__ gamma,
                                                 const float* __restrict__ beta, float* __restrict__ out) {
  int row = blockIdx.x, t = threadIdx.x;
  float2 v = *(const float2*)(pre + (size_t)row * FDIM + t * 2);
  float s = v.x + v.y;
  float ss = v.x * v.x + v.y * v.y;
  for (int off = 32; off; off >>= 1) { s += __shfl_down(s, off); ss += __shfl_down(ss, off); }
  __shared__ float sm[4], sm2[4];
  int wid = t >> 6, lane = t & 63;
  if (lane == 0) { sm[wid] = s; sm2[wid] = ss; }
  __syncthreads();
  if (t == 0) {
    float a = sm[0] + sm[1] + sm[2] + sm[3];
    float b = sm2[0] + sm2[1] + sm2[2] + sm2[3];
    sm[0] = a; sm2[0] = b;
  }
  __syncthreads();
  float mu = sm[0] * (1.f / FDIM);
  float var = sm2[0] * (1.f / FDIM) - mu * mu;
  float inv = rsqrtf(var + EPSv);
  float2 g  = *(const float2*)(gamma + t * 2);
  float2 bb = *(const float2*)(beta + t * 2);
  float2 o;
  o.x = (v.x - mu) * inv * g.x + bb.x;
  o.y = (v.y - mu) * inv * g.y + bb.y;
  *(float2*)(out + (size_t)row * FDIM + t * 2) = o;
}

extern "C" void kernel_launch(void* const* d_in, const int* in_sizes, int n_in,
                              void* d_out, int out_size, void* d_ws, size_t ws_size,
                              hipStream_t stream) {
  const float* x     = (const float*)d_in[0];
  const int*   ei    = (const int*)d_in[1];
  const float* ts    = (const float*)d_in[2];
  const float* W_t   = (const float*)d_in[3];
  const float* b_t   = (const float*)d_in[4];
  const float* W_r   = (const float*)d_in[5];
  const float* gamma = (const float*)d_in[6];
  const float* beta  = (const float*)d_in[7];
  const int*   gt    = (const int*)d_in[8];

  const int E = in_sizes[2];
  const int N = in_sizes[0] / FDIM;
  const int* src = ei;
  const int* dst = ei + E;
  const int totE = E + N;

  // ---- workspace carve (all regions fully rewritten every call) ----
  char* base = (char*)d_ws;
  size_t off = 0;
  auto carve = [&](size_t bytes) -> char* {
    char* r = base + off;
    off = (off + bytes + 255) & ~(size_t)255;
    return r;
  };
  float* tsmax = (float*)carve(4);
  float* deg   = (float*)carve((size_t)N * 4);
  int*   cnt   = (int*)  carve((size_t)N * 4);
  size_t zero_bytes = off;                       // tsmax+deg+cnt need zeroing
  float* dinv  = (float*)carve((size_t)N * 4);
  int*   offs  = (int*)  carve((size_t)(N + 1) * 4);
  int*   cursor= (int*)  carve((size_t)N * 4);
  float* w     = (float*)carve((size_t)totE * 4);
  int*   col   = (int*)  carve((size_t)totE * 4);
  float* val   = (float*)carve((size_t)totE * 4);
  unsigned short* xb  = (unsigned short*)carve((size_t)N * FDIM * 2);   // bf16(x)
  unsigned short* hba = (unsigned short*)carve((size_t)N * FDIM * 2);   // bf16 h ping
  unsigned short* hbb = (unsigned short*)carve((size_t)N * FDIM * 2);   // bf16 h pong
  unsigned short* wtb = (unsigned short*)carve((size_t)FDIM * FDIM * 2);
  unsigned short* wrb = (unsigned short*)carve((size_t)FDIM * FDIM * 2);
  float* C1    = (float*)carve((size_t)N * FDIM * 4);
  float* preLN = (float*)carve((size_t)N * FDIM * 4);

  hipMemsetAsync(d_ws, 0, zero_bytes, stream);

  tsmax_kernel<<<64, 256, 0, stream>>>(ts, E, tsmax);
  edge_w_deg<<<(totE + 255) / 256, 256, 0, stream>>>(src, dst, ts, tsmax, gt, w, deg, cnt, E, N);
  dinv_kernel<<<(N + 255) / 256, 256, 0, stream>>>(deg, dinv, N);
  scan_offsets<<<1, 256, 0, stream>>>(cnt, offs, cursor, N);
  scatter_kernel<<<(totE + 255) / 256, 256, 0, stream>>>(src, dst, w, dinv, cursor, col, val, E, N);

  // casts to bf16 (x and weights; x feeds both the diffusion and the residual GEMM)
  int n8x = N * FDIM / 8;
  cast_bf16<<<(n8x + 255) / 256, 256, 0, stream>>>(x, xb, n8x);
  int n8w = FDIM * FDIM / 8;
  cast_bf16<<<(n8w + 255) / 256, 256, 0, stream>>>(W_t, wtb, n8w);
  cast_bf16<<<(n8w + 255) / 256, 256, 0, stream>>>(W_r, wrb, n8w);

  // 5 Euler steps on bf16 state: xb -> hba -> hbb -> hba -> hbb -> hba
  spmm_step_bf16<<<N, 256, 0, stream>>>(offs, col, val, xb,  hba);
  spmm_step_bf16<<<N, 256, 0, stream>>>(offs, col, val, hba, hbb);
  spmm_step_bf16<<<N, 256, 0, stream>>>(offs, col, val, hbb, hba);
  spmm_step_bf16<<<N, 256, 0, stream>>>(offs, col, val, hba, hbb);
  spmm_step_bf16<<<N, 256, 0, stream>>>(offs, col, val, hbb, hba);

  // GEMM1: C1 = h @ W_t^T ; GEMM2: preLN = relu(C1 + b_t) + x @ W_r^T
  dim3 gg((N + 127) / 128, FDIM / 128);
  gemm_bt<<<gg, 256, 0, stream>>>((const __bf16*)hba, (const __bf16*)wtb, C1, nullptr, nullptr, N);
  gemm_bt<<<gg, 256, 0, stream>>>((const __bf16*)xb, (const __bf16*)wrb, preLN, C1, b_t, N);

  ln_kernel<<<N, 256, 0, stream>>>(preLN, gamma, beta, (float*)d_out);
}

// Round 3
// 554.952 us; speedup vs baseline: 1.4931x; 1.2649x over previous
//
#include <hip/hip_runtime.h>

// Problem constants (from reference)
#define FDIM 512
#define TDK  0.1f   // TIME_DECAY
#define DTs  0.2f   // DIFF_T / NUM_STEPS
#define EPSv 1e-5f

using bf16x8  = __attribute__((ext_vector_type(8))) __bf16;
using floatx4 = __attribute__((ext_vector_type(4))) float;
using ushort8 = __attribute__((ext_vector_type(8))) unsigned short;

__device__ __forceinline__ unsigned short f2bf(float f) {
  unsigned int u = __float_as_uint(f);
  u += 0x7fffu + ((u >> 16) & 1u);   // RNE
  return (unsigned short)(u >> 16);
}

// ---------------- ts.max() over timestamps (graph_time folded in later) -------
__global__ __launch_bounds__(256) void tsmax_kernel(const float* __restrict__ ts, int E,
                                                    float* __restrict__ out) {
  float m = 0.f;  // timestamps >= 0
  for (int i = blockIdx.x * blockDim.x + threadIdx.x; i < E; i += gridDim.x * blockDim.x)
    m = fmaxf(m, ts[i]);
  for (int off = 32; off; off >>= 1) m = fmaxf(m, __shfl_down(m, off));
  __shared__ float sm[4];
  int wid = threadIdx.x >> 6, lane = threadIdx.x & 63;
  if (lane == 0) sm[wid] = m;
  __syncthreads();
  if (threadIdx.x == 0) {
    float mm = fmaxf(fmaxf(sm[0], sm[1]), fmaxf(sm[2], sm[3]));
    atomicMax((int*)out, __float_as_int(mm));  // positive floats: int order == float order
  }
}

// -------- per-edge decay weight + weighted degree (dst) + CSR row counts ------
__global__ __launch_bounds__(256) void edge_w_deg(const int* __restrict__ src, const int* __restrict__ dst,
                                                  const float* __restrict__ ts, const float* __restrict__ tsmax_p,
                                                  const int* __restrict__ gt_p,
                                                  float* __restrict__ w, float* __restrict__ deg,
                                                  int* __restrict__ cnt, int E, int N) {
  int e = blockIdx.x * blockDim.x + threadIdx.x;
  int total = E + N;
  if (e >= total) return;
  float gtf = (float)(*gt_p);
  float tm = fmaxf(*tsmax_p, gtf);
  int d; float t;
  if (e < E) { d = dst[e]; t = ts[e]; }
  else       { d = e - E;  t = gtf; }
  float wv = expf(-TDK * (tm - t));
  w[e] = wv;
  atomicAdd(&deg[d], wv);
  atomicAdd(&cnt[d], 1);
}

__global__ __launch_bounds__(256) void dinv_kernel(const float* __restrict__ deg, float* __restrict__ dinv, int N) {
  int i = blockIdx.x * blockDim.x + threadIdx.x;
  if (i >= N) return;
  float d = deg[i];
  dinv[i] = (d > 0.f) ? rsqrtf(d) : 0.f;
}

// ---------------- single-block exclusive scan for CSR offsets -----------------
__global__ __launch_bounds__(256) void scan_offsets(const int* __restrict__ cnt, int* __restrict__ offs,
                                                    int* __restrict__ cursor, int n) {
  __shared__ int sums[256];
  int tid = threadIdx.x;
  int chunk = (n + 255) >> 8;
  int start = tid * chunk;
  int end = min(start + chunk, n);
  int s = 0;
  for (int i = start; i < end; ++i) s += cnt[i];
  sums[tid] = s;
  __syncthreads();
  for (int off = 1; off < 256; off <<= 1) {
    int v = (tid >= off) ? sums[tid - off] : 0;
    __syncthreads();
    sums[tid] += v;
    __syncthreads();
  }
  int prefix = (tid == 0) ? 0 : sums[tid - 1];
  for (int i = start; i < end; ++i) {
    offs[i] = prefix; cursor[i] = prefix; prefix += cnt[i];
  }
  if (tid == 255) offs[n] = prefix;
}

// -------- scatter edges into CSR (col=src, val = dinv[src]*w*dinv[dst]) -------
__global__ __launch_bounds__(256) void scatter_kernel(const int* __restrict__ src, const int* __restrict__ dst,
                                                      const float* __restrict__ w, const float* __restrict__ dinv,
                                                      int* __restrict__ cursor, int* __restrict__ col,
                                                      float* __restrict__ val, int E, int N) {
  int e = blockIdx.x * blockDim.x + threadIdx.x;
  if (e >= E + N) return;
  int s, d;
  if (e < E) { s = src[e]; d = dst[e]; }
  else       { s = d = e - E; }
  int pos = atomicAdd(&cursor[d], 1);
  col[pos] = s;
  val[pos] = dinv[s] * w[e] * dinv[d];
}

// ------------- one diffusion step, bf16 state: h_out = (1-dt)h_in + dt*(A h_in)
// ONE WAVE PER ROW: 64 lanes x 16 B (bf16x8) = the full 1 KB feature row.
// Edge loop manually unrolled x4 with batched col/val loads so 4 dwordx4
// gathers are in flight per wave (latency-bound fix; R2 had 1 in flight).
__device__ __forceinline__ void acc8(uint4 u, float v, float* a) {
  a[0] += v * __uint_as_float(u.x << 16);
  a[1] += v * __uint_as_float(u.x & 0xffff0000u);
  a[2] += v * __uint_as_float(u.y << 16);
  a[3] += v * __uint_as_float(u.y & 0xffff0000u);
  a[4] += v * __uint_as_float(u.z << 16);
  a[5] += v * __uint_as_float(u.z & 0xffff0000u);
  a[6] += v * __uint_as_float(u.w << 16);
  a[7] += v * __uint_as_float(u.w & 0xffff0000u);
}

__global__ __launch_bounds__(256) void spmm_step_bf16(const int* __restrict__ offs, const int* __restrict__ col,
                                                      const float* __restrict__ val,
                                                      const unsigned short* __restrict__ h_in,
                                                      unsigned short* __restrict__ h_out, int N) {
  int row = blockIdx.x * 4 + (threadIdx.x >> 6);
  if (row >= N) return;
  int lane = threadIdx.x & 63;
  int fo = lane * 8;  // 8 bf16 = 16 B per lane
  int s = offs[row], e = offs[row + 1];
  float a[8] = {0.f, 0.f, 0.f, 0.f, 0.f, 0.f, 0.f, 0.f};
  int j = s;
  for (; j + 4 <= e; j += 4) {
    int c0 = col[j], c1 = col[j + 1], c2 = col[j + 2], c3 = col[j + 3];
    float v0 = val[j], v1 = val[j + 1], v2 = val[j + 2], v3 = val[j + 3];
    uint4 u0 = *(const uint4*)(h_in + (size_t)c0 * FDIM + fo);
    uint4 u1 = *(const uint4*)(h_in + (size_t)c1 * FDIM + fo);
    uint4 u2 = *(const uint4*)(h_in + (size_t)c2 * FDIM + fo);
    uint4 u3 = *(const uint4*)(h_in + (size_t)c3 * FDIM + fo);
    acc8(u0, v0, a); acc8(u1, v1, a); acc8(u2, v2, a); acc8(u3, v3, a);
  }
  for (; j < e; ++j) {
    int c = col[j];
    float v = val[j];
    uint4 u = *(const uint4*)(h_in + (size_t)c * FDIM + fo);
    acc8(u, v, a);
  }
  // self term: h + dt*(Ah - h)
  uint4 ud = *(const uint4*)(h_in + (size_t)row * FDIM + fo);
  float hd[8];
  hd[0] = __uint_as_float(ud.x << 16); hd[1] = __uint_as_float(ud.x & 0xffff0000u);
  hd[2] = __uint_as_float(ud.y << 16); hd[3] = __uint_as_float(ud.y & 0xffff0000u);
  hd[4] = __uint_as_float(ud.z << 16); hd[5] = __uint_as_float(ud.z & 0xffff0000u);
  hd[6] = __uint_as_float(ud.w << 16); hd[7] = __uint_as_float(ud.w & 0xffff0000u);
  uint4 o;
  unsigned int p0, p1;
#define PACK(k0, k1, dst_)                                        \
  { float o0 = hd[k0] + DTs * (a[k0] - hd[k0]);                   \
    float o1 = hd[k1] + DTs * (a[k1] - hd[k1]);                   \
    p0 = f2bf(o0); p1 = f2bf(o1); dst_ = p0 | (p1 << 16); }
  PACK(0, 1, o.x) PACK(2, 3, o.y) PACK(4, 5, o.z) PACK(6, 7, o.w)
#undef PACK
  *(uint4*)(h_out + (size_t)row * FDIM + fo) = o;
}

// ------------------------------ fp32 -> bf16 cast -----------------------------
__global__ __launch_bounds__(256) void cast_bf16(const float* __restrict__ srcp,
                                                 unsigned short* __restrict__ dstp, int n8) {
  int i = blockIdx.x * blockDim.x + threadIdx.x;
  if (i >= n8) return;
  const float4 v0 = *(const float4*)(srcp + (size_t)i * 8);
  const float4 v1 = *(const float4*)(srcp + (size_t)i * 8 + 4);
  ushort8 o;
  o[0] = f2bf(v0.x); o[1] = f2bf(v0.y); o[2] = f2bf(v0.z); o[3] = f2bf(v0.w);
  o[4] = f2bf(v1.x); o[5] = f2bf(v1.y); o[6] = f2bf(v1.z); o[7] = f2bf(v1.w);
  *(ushort8*)(dstp + (size_t)i * 8) = o;
}

// --------------------- bf16 MFMA GEMM: C = A @ B^T (B is [n][k]) --------------
// block = 256 thr (4 waves in 2x2), tile 128x128, BK=32, LDS row stride 40 (pad)
// If C1 != nullptr: C = relu(C1 + bias) + A@B^T  (fused epilogue for GEMM2)
__global__ __launch_bounds__(256) void gemm_bt(const __bf16* __restrict__ A, const __bf16* __restrict__ B,
                                               float* __restrict__ C, const float* __restrict__ C1,
                                               const float* __restrict__ bias, int M) {
  __shared__ __bf16 a_s[128 * 40];
  __shared__ __bf16 b_s[128 * 40];
  int tid = threadIdx.x;
  int wid = tid >> 6, lane = tid & 63;
  int wm = wid & 1, wn = wid >> 1;
  int lane15 = lane & 15, quad = lane >> 4;
  int m0 = blockIdx.x * 128;
  int n0 = blockIdx.y * 128;

  floatx4 acc[4][4];
  floatx4 z4; z4[0] = 0.f; z4[1] = 0.f; z4[2] = 0.f; z4[3] = 0.f;
#pragma unroll
  for (int im = 0; im < 4; ++im)
#pragma unroll
    for (int in = 0; in < 4; ++in) acc[im][in] = z4;

  for (int kt = 0; kt < FDIM; kt += 32) {
#pragma unroll
    for (int i = tid; i < 512; i += 256) {
      int row = i >> 2, seg = i & 3;
      int gm = m0 + row; if (gm >= M) gm = M - 1;
      bf16x8 v = *(const bf16x8*)(A + (size_t)gm * FDIM + kt + seg * 8);
      *(bf16x8*)(a_s + row * 40 + seg * 8) = v;
    }
#pragma unroll
    for (int i = tid; i < 512; i += 256) {
      int row = i >> 2, seg = i & 3;
      bf16x8 v = *(const bf16x8*)(B + (size_t)(n0 + row) * FDIM + kt + seg * 8);
      *(bf16x8*)(b_s + row * 40 + seg * 8) = v;
    }
    __syncthreads();
    bf16x8 af[4], bf[4];
#pragma unroll
    for (int im = 0; im < 4; ++im)
      af[im] = *(const bf16x8*)(a_s + (wm * 64 + im * 16 + lane15) * 40 + quad * 8);
#pragma unroll
    for (int in = 0; in < 4; ++in)
      bf[in] = *(const bf16x8*)(b_s + (wn * 64 + in * 16 + lane15) * 40 + quad * 8);
#pragma unroll
    for (int im = 0; im < 4; ++im)
#pragma unroll
      for (int in = 0; in < 4; ++in)
        acc[im][in] = __builtin_amdgcn_mfma_f32_16x16x32_bf16(af[im], bf[in], acc[im][in], 0, 0, 0);
    __syncthreads();
  }

  // epilogue: C/D layout col=lane&15, row=quad*4+reg
#pragma unroll
  for (int im = 0; im < 4; ++im) {
#pragma unroll
    for (int in = 0; in < 4; ++in) {
#pragma unroll
      for (int r = 0; r < 4; ++r) {
        int m = m0 + wm * 64 + im * 16 + quad * 4 + r;
        int n = n0 + wn * 64 + in * 16 + lane15;
        if (m < M) {
          float v = acc[im][in][r];
          if (C1) {
            float p = C1[(size_t)m * FDIM + n] + bias[n];
            v += fmaxf(p, 0.f);
          }
          C[(size_t)m * FDIM + n] = v;
        }
      }
    }
  }
}

// ------------------------------ rowwise LayerNorm -----------------------------
__global__ __launch_bounds__(256) void ln_kernel(const float* __restrict__ pre, const float* __restrict__ gamma,
                                                 const float* __restrict__ beta, float* __restrict__ out) {
  int row = blockIdx.x, t = threadIdx.x;
  float2 v = *(const float2*)(pre + (size_t)row * FDIM + t * 2);
  float s = v.x + v.y;
  float ss = v.x * v.x + v.y * v.y;
  for (int off = 32; off; off >>= 1) { s += __shfl_down(s, off); ss += __shfl_down(ss, off); }
  __shared__ float sm[4], sm2[4];
  int wid = t >> 6, lane = t & 63;
  if (lane == 0) { sm[wid] = s; sm2[wid] = ss; }
  __syncthreads();
  if (t == 0) {
    float a = sm[0] + sm[1] + sm[2] + sm[3];
    float b = sm2[0] + sm2[1] + sm2[2] + sm2[3];
    sm[0] = a; sm2[0] = b;
  }
  __syncthreads();
  float mu = sm[0] * (1.f / FDIM);
  float var = sm2[0] * (1.f / FDIM) - mu * mu;
  float inv = rsqrtf(var + EPSv);
  float2 g  = *(const float2*)(gamma + t * 2);
  float2 bb = *(const float2*)(beta + t * 2);
  float2 o;
  o.x = (v.x - mu) * inv * g.x + bb.x;
  o.y = (v.y - mu) * inv * g.y + bb.y;
  *(float2*)(out + (size_t)row * FDIM + t * 2) = o;
}

extern "C" void kernel_launch(void* const* d_in, const int* in_sizes, int n_in,
                              void* d_out, int out_size, void* d_ws, size_t ws_size,
                              hipStream_t stream) {
  const float* x     = (const float*)d_in[0];
  const int*   ei    = (const int*)d_in[1];
  const float* ts    = (const float*)d_in[2];
  const float* W_t   = (const float*)d_in[3];
  const float* b_t   = (const float*)d_in[4];
  const float* W_r   = (const float*)d_in[5];
  const float* gamma = (const float*)d_in[6];
  const float* beta  = (const float*)d_in[7];
  const int*   gt    = (const int*)d_in[8];

  const int E = in_sizes[2];
  const int N = in_sizes[0] / FDIM;
  const int* src = ei;
  const int* dst = ei + E;
  const int totE = E + N;

  // ---- workspace carve (all regions fully rewritten every call) ----
  char* base = (char*)d_ws;
  size_t off = 0;
  auto carve = [&](size_t bytes) -> char* {
    char* r = base + off;
    off = (off + bytes + 255) & ~(size_t)255;
    return r;
  };
  float* tsmax = (float*)carve(4);
  float* deg   = (float*)carve((size_t)N * 4);
  int*   cnt   = (int*)  carve((size_t)N * 4);
  size_t zero_bytes = off;                       // tsmax+deg+cnt need zeroing
  float* dinv  = (float*)carve((size_t)N * 4);
  int*   offs  = (int*)  carve((size_t)(N + 1) * 4);
  int*   cursor= (int*)  carve((size_t)N * 4);
  float* w     = (float*)carve((size_t)totE * 4);
  int*   col   = (int*)  carve((size_t)totE * 4);
  float* val   = (float*)carve((size_t)totE * 4);
  unsigned short* xb  = (unsigned short*)carve((size_t)N * FDIM * 2);   // bf16(x)
  unsigned short* hba = (unsigned short*)carve((size_t)N * FDIM * 2);   // bf16 h ping
  unsigned short* hbb = (unsigned short*)carve((size_t)N * FDIM * 2);   // bf16 h pong
  unsigned short* wtb = (unsigned short*)carve((size_t)FDIM * FDIM * 2);
  unsigned short* wrb = (unsigned short*)carve((size_t)FDIM * FDIM * 2);
  float* C1    = (float*)carve((size_t)N * FDIM * 4);
  float* preLN = (float*)carve((size_t)N * FDIM * 4);

  hipMemsetAsync(d_ws, 0, zero_bytes, stream);

  tsmax_kernel<<<64, 256, 0, stream>>>(ts, E, tsmax);
  edge_w_deg<<<(totE + 255) / 256, 256, 0, stream>>>(src, dst, ts, tsmax, gt, w, deg, cnt, E, N);
  dinv_kernel<<<(N + 255) / 256, 256, 0, stream>>>(deg, dinv, N);
  scan_offsets<<<1, 256, 0, stream>>>(cnt, offs, cursor, N);
  scatter_kernel<<<(totE + 255) / 256, 256, 0, stream>>>(src, dst, w, dinv, cursor, col, val, E, N);

  // casts to bf16 (x and weights; x feeds both the diffusion and the residual GEMM)
  int n8x = N * FDIM / 8;
  cast_bf16<<<(n8x + 255) / 256, 256, 0, stream>>>(x, xb, n8x);
  int n8w = FDIM * FDIM / 8;
  cast_bf16<<<(n8w + 255) / 256, 256, 0, stream>>>(W_t, wtb, n8w);
  cast_bf16<<<(n8w + 255) / 256, 256, 0, stream>>>(W_r, wrb, n8w);

  // 5 Euler steps on bf16 state: xb -> hba -> hbb -> hba -> hbb -> hba
  int sg = (N + 3) / 4;
  spmm_step_bf16<<<sg, 256, 0, stream>>>(offs, col, val, xb,  hba, N);
  spmm_step_bf16<<<sg, 256, 0, stream>>>(offs, col, val, hba, hbb, N);
  spmm_step_bf16<<<sg, 256, 0, stream>>>(offs, col, val, hbb, hba, N);
  spmm_step_bf16<<<sg, 256, 0, stream>>>(offs, col, val, hba, hbb, N);
  spmm_step_bf16<<<sg, 256, 0, stream>>>(offs, col, val, hbb, hba, N);

  // GEMM1: C1 = h @ W_t^T ; GEMM2: preLN = relu(C1 + b_t) + x @ W_r^T
  dim3 gg((N + 127) / 128, FDIM / 128);
  gemm_bt<<<gg, 256, 0, stream>>>((const __bf16*)hba, (const __bf16*)wtb, C1, nullptr, nullptr, N);
  gemm_bt<<<gg, 256, 0, stream>>>((const __bf16*)xb, (const __bf16*)wrb, preLN, C1, b_t, N);

  ln_kernel<<<N, 256, 0, stream>>>(preLN, gamma, beta, (float*)d_out);
}